// Round 5
// baseline (1995.029 us; speedup 1.0000x reference)
//
#include <hip/hip_runtime.h>
#include <math.h>

#define THREADS 256
// fp32-vs-fp64 p error is <~3e-6 worst case; 1e-4 margin is ~30x safety.
#define P_MARGIN 1e-4f

// Exact JAX threefry2x32 (20 rounds, key schedule every 4), key = (0, 42).
// Partitionable stream: bits[j] = o0 ^ o1 of threefry2x32(key, 0, j).
__device__ __forceinline__ void tf2x32(unsigned x0, unsigned x1,
                                       unsigned &o0, unsigned &o1) {
  const unsigned k0 = 0u;
  const unsigned k1 = 42u;
  const unsigned k2 = 0x1BD11BDAu ^ k0 ^ k1;
  x0 += k0; x1 += k1;
#define TF_R(r) { x0 += x1; x1 = (x1 << (r)) | (x1 >> (32 - (r))); x1 ^= x0; }
  TF_R(13) TF_R(15) TF_R(26) TF_R(6)
  x0 += k1; x1 += k2 + 1u;
  TF_R(17) TF_R(29) TF_R(16) TF_R(24)
  x0 += k2; x1 += k0 + 2u;
  TF_R(13) TF_R(15) TF_R(26) TF_R(6)
  x0 += k0; x1 += k1 + 3u;
  TF_R(17) TF_R(29) TF_R(16) TF_R(24)
  x0 += k1; x1 += k2 + 4u;
  TF_R(13) TF_R(15) TF_R(26) TF_R(6)
  x0 += k2; x1 += k0 + 5u;
#undef TF_R
  o0 = x0; o1 = x1;
}

// ---------------- Pass 1: fp32, scalar-path weights ----------------
// All weight/bias indices are compile-time constants off uniform kernel-arg
// pointers -> LLVM emits s_load (scalar cache); one load per wave serves all
// 64 rows. No LDS at all. k-outer/n-inner so weight rows are contiguous and
// mergeable into s_load_dwordx4+.
__global__ __launch_bounds__(THREADS, 4)
void wtf_fast_kernel(const float* __restrict__ events,
                     const float* __restrict__ W1, const float* __restrict__ b1,
                     const float* __restrict__ g1, const float* __restrict__ be1,
                     const float* __restrict__ W2, const float* __restrict__ b2,
                     const float* __restrict__ g2, const float* __restrict__ be2,
                     const float* __restrict__ W3, const float* __restrict__ b3,
                     const float* __restrict__ g3, const float* __restrict__ be3,
                     const float* __restrict__ W4, const float* __restrict__ b4,
                     const float* __restrict__ W5, const float* __restrict__ b5,
                     float* __restrict__ out_chosen,
                     float* __restrict__ out_logp,
                     unsigned* __restrict__ fixlist,  // [0]=count, rows at [1+i]
                     unsigned fixcap,
                     int B) {
  const int b = blockIdx.x * THREADS + threadIdx.x;
  if (b >= B) return;

  const float rden = (float)(1.0 / sqrt(1.0 + 1e-5));

  float x[32];
  const float4* ev4 = reinterpret_cast<const float4*>(events) + (size_t)b * 8;
#pragma unroll
  for (int q = 0; q < 8; ++q) {
    float4 v = ev4[q];
    x[4 * q + 0] = v.x; x[4 * q + 1] = v.y; x[4 * q + 2] = v.z; x[4 * q + 3] = v.w;
  }

  // layer 1: 32 -> 50, BN(eval) + ReLU
  float a1[50];
#pragma unroll
  for (int n = 0; n < 50; ++n) a1[n] = b1[n];
#pragma unroll
  for (int k = 0; k < 32; ++k) {
    const float xk = x[k];
#pragma unroll
    for (int n = 0; n < 50; ++n) a1[n] = fmaf(xk, W1[k * 50 + n], a1[n]);
  }
#pragma unroll
  for (int n = 0; n < 50; ++n) {
    float s = fmaf(a1[n], g1[n] * rden, be1[n]);
    a1[n] = fmaxf(s, 0.f);
  }

  // layer 2: 50 -> 30, BN(eval) + ReLU
  float a2[30];
#pragma unroll
  for (int n = 0; n < 30; ++n) a2[n] = b2[n];
#pragma unroll
  for (int k = 0; k < 50; ++k) {
    const float ak = a1[k];
#pragma unroll
    for (int n = 0; n < 30; ++n) a2[n] = fmaf(ak, W2[k * 30 + n], a2[n]);
  }
#pragma unroll
  for (int n = 0; n < 30; ++n) {
    float s = fmaf(a2[n], g2[n] * rden, be2[n]);
    a2[n] = fmaxf(s, 0.f);
  }

  // layer 3: 30 -> 20, BN(eval) + ReLU
  float a3[20];
#pragma unroll
  for (int n = 0; n < 20; ++n) a3[n] = b3[n];
#pragma unroll
  for (int k = 0; k < 30; ++k) {
    const float ak = a2[k];
#pragma unroll
    for (int n = 0; n < 20; ++n) a3[n] = fmaf(ak, W3[k * 20 + n], a3[n]);
  }
#pragma unroll
  for (int n = 0; n < 20; ++n) {
    float s = fmaf(a3[n], g3[n] * rden, be3[n]);
    a3[n] = fmaxf(s, 0.f);
  }

  // layer 4: 20 -> 15, ReLU (no BN)
  float a4[15];
#pragma unroll
  for (int n = 0; n < 15; ++n) a4[n] = b4[n];
#pragma unroll
  for (int k = 0; k < 20; ++k) {
    const float ak = a3[k];
#pragma unroll
    for (int n = 0; n < 15; ++n) a4[n] = fmaf(ak, W4[k * 15 + n], a4[n]);
  }
#pragma unroll
  for (int n = 0; n < 15; ++n) a4[n] = fmaxf(a4[n], 0.f);

  // layer 5: 15 -> 8, sigmoid
  float p[8];
#pragma unroll
  for (int n = 0; n < 8; ++n) p[n] = b5[n];
#pragma unroll
  for (int k = 0; k < 15; ++k) {
    const float ak = a4[k];
#pragma unroll
    for (int n = 0; n < 8; ++n) p[n] = fmaf(ak, W5[k * 8 + n], p[n]);
  }
#pragma unroll
  for (int n = 0; n < 8; ++n) p[n] = 1.f / (1.f + expf(-p[n]));

  // bernoulli(1-p) via partitionable threefry + margin flag
  bool need = false;
  float prod = 1.f;
  float ch[8];
#pragma unroll
  for (int w = 0; w < 8; ++w) {
    unsigned j = 8u * (unsigned)b + (unsigned)w, o0, o1;
    tf2x32(0u, j, o0, o1);
    unsigned bits = o0 ^ o1;
    float u = __uint_as_float(0x3F800000u | (bits >> 9)) - 1.f;
    float thr = 1.f - p[w];
    bool choice = u < thr;
    need = need || (fabsf(u - thr) < P_MARGIN);
    ch[w] = choice ? 0.f : 1.f;
    prod *= choice ? thr : p[w];
  }
  if (need) {
    unsigned i = atomicAdd(&fixlist[0], 1u);
    if (i < fixcap) fixlist[1 + i] = (unsigned)b;
  }

  float4* oc = reinterpret_cast<float4*>(out_chosen) + (size_t)b * 2;
  oc[0] = make_float4(ch[0], ch[1], ch[2], ch[3]);
  oc[1] = make_float4(ch[4], ch[5], ch[6], ch[7]);
  out_logp[b] = logf(prod);
}

// ---------------- Pass 2: fp64 repair, one THREAD per flagged row --------
// Exactly R2's fp64 arithmetic (validated), weights via the same uniform/
// scalar-load path (loop counters are wave-uniform), no LDS, no spills.
__global__ __launch_bounds__(64)
void wtf_fix_kernel(const float* __restrict__ events,
                    const float* __restrict__ W1, const float* __restrict__ b1,
                    const float* __restrict__ g1, const float* __restrict__ be1,
                    const float* __restrict__ W2, const float* __restrict__ b2,
                    const float* __restrict__ g2, const float* __restrict__ be2,
                    const float* __restrict__ W3, const float* __restrict__ b3,
                    const float* __restrict__ g3, const float* __restrict__ be3,
                    const float* __restrict__ W4, const float* __restrict__ b4,
                    const float* __restrict__ W5, const float* __restrict__ b5,
                    float* __restrict__ out_chosen,
                    float* __restrict__ out_logp,
                    const unsigned* __restrict__ fixlist,
                    unsigned fixcap,
                    int B) {
  const unsigned raw = fixlist[0];
  const unsigned cnt = raw < fixcap ? raw : fixcap;
  const double denom = sqrt(1.0 + 1e-5);
  const unsigned stride = gridDim.x * 64u;

  for (unsigned idx = blockIdx.x * 64u + threadIdx.x; idx < cnt; idx += stride) {
    const int b = (int)fixlist[1 + idx];

    double x[32];
    const float4* ev4 = reinterpret_cast<const float4*>(events) + (size_t)b * 8;
#pragma unroll
    for (int q = 0; q < 8; ++q) {
      float4 v = ev4[q];
      x[4 * q + 0] = (double)v.x; x[4 * q + 1] = (double)v.y;
      x[4 * q + 2] = (double)v.z; x[4 * q + 3] = (double)v.w;
    }

    double a1[50];
#pragma unroll
    for (int n = 0; n < 50; ++n) {
      double acc = 0.0;
#pragma unroll
      for (int k = 0; k < 32; ++k) acc = fma(x[k], (double)W1[k * 50 + n], acc);
      acc += (double)b1[n];
      acc = acc * ((double)g1[n] / denom) + (double)be1[n];
      a1[n] = acc > 0.0 ? acc : 0.0;
    }
    double a2[30];
#pragma unroll
    for (int n = 0; n < 30; ++n) {
      double acc = 0.0;
#pragma unroll
      for (int k = 0; k < 50; ++k) acc = fma(a1[k], (double)W2[k * 30 + n], acc);
      acc += (double)b2[n];
      acc = acc * ((double)g2[n] / denom) + (double)be2[n];
      a2[n] = acc > 0.0 ? acc : 0.0;
    }
    double a3[20];
#pragma unroll
    for (int n = 0; n < 20; ++n) {
      double acc = 0.0;
#pragma unroll
      for (int k = 0; k < 30; ++k) acc = fma(a2[k], (double)W3[k * 20 + n], acc);
      acc += (double)b3[n];
      acc = acc * ((double)g3[n] / denom) + (double)be3[n];
      a3[n] = acc > 0.0 ? acc : 0.0;
    }
    double a4[15];
#pragma unroll
    for (int n = 0; n < 15; ++n) {
      double acc = 0.0;
#pragma unroll
      for (int k = 0; k < 20; ++k) acc = fma(a3[k], (double)W4[k * 15 + n], acc);
      acc += (double)b4[n];
      a4[n] = acc > 0.0 ? acc : 0.0;
    }
    double p[8];
#pragma unroll
    for (int n = 0; n < 8; ++n) {
      double acc = 0.0;
#pragma unroll
      for (int k = 0; k < 15; ++k) acc = fma(a4[k], (double)W5[k * 8 + n], acc);
      acc += (double)b5[n];
      p[n] = 1.0 / (1.0 + exp(-acc));
    }

    double prod = 1.0;
    float ch[8];
#pragma unroll
    for (int w = 0; w < 8; ++w) {
      unsigned j = 8u * (unsigned)b + (unsigned)w, o0, o1;
      tf2x32(0u, j, o0, o1);
      unsigned bits = o0 ^ o1;
      float u = __uint_as_float(0x3F800000u | (bits >> 9)) - 1.f;
      double thr = 1.0 - p[w];
      bool choice = ((double)u < thr);
      ch[w] = choice ? 0.f : 1.f;
      prod *= choice ? thr : p[w];
    }
    float4* oc = reinterpret_cast<float4*>(out_chosen) + (size_t)b * 2;
    oc[0] = make_float4(ch[0], ch[1], ch[2], ch[3]);
    oc[1] = make_float4(ch[4], ch[5], ch[6], ch[7]);
    out_logp[b] = (float)log(prod);
  }
}

extern "C" void kernel_launch(void* const* d_in, const int* in_sizes, int n_in,
                              void* d_out, int out_size, void* d_ws, size_t ws_size,
                              hipStream_t stream) {
  const float* events = (const float*)d_in[0];
  const float* W1  = (const float*)d_in[1];
  const float* b1  = (const float*)d_in[2];
  const float* g1  = (const float*)d_in[3];
  const float* be1 = (const float*)d_in[4];
  const float* W2  = (const float*)d_in[5];
  const float* b2  = (const float*)d_in[6];
  const float* g2  = (const float*)d_in[7];
  const float* be2 = (const float*)d_in[8];
  const float* W3  = (const float*)d_in[9];
  const float* b3  = (const float*)d_in[10];
  const float* g3  = (const float*)d_in[11];
  const float* be3 = (const float*)d_in[12];
  const float* W4  = (const float*)d_in[13];
  const float* b4  = (const float*)d_in[14];
  const float* W5  = (const float*)d_in[15];
  const float* b5  = (const float*)d_in[16];

  const int B = in_sizes[0] / 32;  // 524288
  float* out = (float*)d_out;
  float* out_chosen = out;                   // (B, 8)
  float* out_logp   = out + (size_t)B * 8;   // (B,)
  unsigned* fixlist = (unsigned*)d_ws;       // [0]=count, rows at [1+i]
  unsigned fixcap = (unsigned)(ws_size / sizeof(unsigned) - 1);
  if (fixcap > (unsigned)B) fixcap = (unsigned)B;

  hipMemsetAsync(d_ws, 0, sizeof(unsigned), stream);  // zero the counter

  const int blocks = (B + THREADS - 1) / THREADS;
  hipLaunchKernelGGL(wtf_fast_kernel, dim3(blocks), dim3(THREADS), 0, stream,
                     events, W1, b1, g1, be1, W2, b2, g2, be2,
                     W3, b3, g3, be3, W4, b4, W5, b5,
                     out_chosen, out_logp, fixlist, fixcap, B);
  hipLaunchKernelGGL(wtf_fix_kernel, dim3(1024), dim3(64), 0, stream,
                     events, W1, b1, g1, be1, W2, b2, g2, be2,
                     W3, b3, g3, be3, W4, b4, W5, b5,
                     out_chosen, out_logp, fixlist, fixcap, B);
}